// Round 15
// baseline (286.943 us; speedup 1.0000x reference)
//
#include <hip/hip_runtime.h>

typedef unsigned short u16;
typedef _Float16  f16x8  __attribute__((ext_vector_type(8)));
typedef _Float16  f16x4  __attribute__((ext_vector_type(4)));
typedef _Float16  f16x2  __attribute__((ext_vector_type(2)));
typedef float     f32x4  __attribute__((ext_vector_type(4)));

#define MFMA_F16(a,b,c)  __builtin_amdgcn_mfma_f32_16x16x32_f16(a,b,c,0,0,0)
#define PKRTZ(a,b) __builtin_bit_cast(f16x2, __builtin_amdgcn_cvt_pkrtz((a),(b)))

#define NTOK 64
#define DIM_ 128
#define SCALE_ 0.17677669529663687f   // 32^-0.5

// LDS geometry (u16 units) — 35840 B total: 3 blocks/CU if usable LDS >= 107520
// (usable >= 108544 proven by R8's 2x54272 co-residency).
// Per-head region HREG 4480: q[64][36] | k[64][34].
// Overlays (all unpermuted): P-halves [64][36] cols 0..31 over q-area
// (tokens 32hx..32hx+31, two sequential passes); vT[32][68] over k-area
// (exact 2176 fit); attn-out [64][36] over q-area (fits: 63*36+31 < 2304).
#define HREG 4480
#define KOFF 2304      // 64*36
#define SQ   36        // q / qf / P-half / attn-out stride (72-B rows)
#define SK   34        // k / kf stride (68-B rows, 4-B aligned; R9-proven)
#define SVT  68        // vT stride (136-B rows), 32*68 = 2176 = k-area exact
#define SMEM_U16 17920 // 4*HREG = 35840 B

__device__ __forceinline__ u16 f2h_u(float x) {
    _Float16 h = (_Float16)x;
    return __builtin_bit_cast(u16, h);
}

// ---------------- prep: repack f32 weights into fp16 MFMA B-fragment order ----------------
// ws: u16 frags [192*512]: [wq 0..31 | wkv 32..95 | wq_f 96..127 | wkv_f(k-half) 128..159 | wproj 160..191]
__global__ void wja_prep(const float* __restrict__ wq, const float* __restrict__ wkv,
                         const float* __restrict__ wq_f, const float* __restrict__ wkv_f,
                         const float* __restrict__ wproj, u16* __restrict__ ws)
{
    const int blk = blockIdx.x;
    const int l = threadIdx.x;          // 64 threads
    const float* W; int ldw, colbase;
    if (blk < 32)       { W = wq;    ldw = 128; colbase = (blk      >> 2) * 16; }
    else if (blk < 96)  { W = wkv;   ldw = 256; colbase = ((blk- 32) >> 2) * 16; }
    else if (blk < 128) { W = wq_f;  ldw = 128; colbase = ((blk- 96) >> 2) * 16; }
    else if (blk < 160) { W = wkv_f; ldw = 256; colbase = ((blk-128) >> 2) * 16; }
    else                { W = wproj; ldw = 128; colbase = ((blk-160) >> 2) * 16; }
    const int ks = blk & 3;
    const int m = l & 15, g = l >> 4;
    u16* dst = ws + blk * 512 + l * 8;
    #pragma unroll
    for (int i = 0; i < 8; ++i)
        dst[i] = f2h_u(W[(size_t)(32*ks + 8*g + i) * ldw + colbase + m]);
}

// ---------------- fused window joint attention ----------------
// 1 block = 1 window; 4 waves. Stage-A: wave w = 16-token rowtile (all heads).
// Attention: wave w = head w. 6 barriers. v-GEMM deferred until after Sf so
// vT overlays dead kf and P overlays dead qf -> 35840 B LDS.
// No permutation, no exec-masked writes (R14's bundled complexity failed
// correctness); every MFMA read pattern matches an already-passing round.
// Bias stays INLINE MATH (R12: table+branch -> VGPR 128 + 680 MB spill).
__global__ __launch_bounds__(256, 2)
void wja_fused(
    const float* __restrict__ x, const float* __restrict__ f,
    const float* __restrict__ bq, const float* __restrict__ bkv,
    const float* __restrict__ bq_f, const float* __restrict__ bkv_f,
    const float* __restrict__ bproj, const float* __restrict__ btab,
    const u16* __restrict__ ws, float* __restrict__ out)
{
    __shared__ __align__(16) u16 smem[SMEM_U16];
    const int b    = blockIdx.x;
    const int tid  = threadIdx.x;
    const int w    = tid >> 6;        // stage-A: rowtile; attention: head
    const int lane = tid & 63;
    const int g    = lane >> 4;
    const int c    = lane & 15;
    const f32x4 zf4 = {0.f, 0.f, 0.f, 0.f};

    u16* const hb = smem + w * HREG;  // own head region in attention phases

    const float* const xb = x + (size_t)b * (NTOK * DIM_);
    const float* const fb = f + (size_t)b * (NTOK * DIM_);

    // 8 f32 -> f16x8 via two vector loads + 4 packed cvt (RTZ)
    auto ldf16 = [](const float* p) -> f16x8 {
        f32x4 v0 = *(const f32x4*)p;
        f32x4 v1 = *(const f32x4*)(p + 4);
        struct Q { f16x2 a, b, c, d; } t;
        t.a = PKRTZ(v0[0], v0[1]);
        t.b = PKRTZ(v0[2], v0[3]);
        t.c = PKRTZ(v1[0], v1[1]);
        t.d = PKRTZ(v1[2], v1[3]);
        return __builtin_bit_cast(f16x8, t);
    };
    // 8 fp16 from LDS at 8-B alignment: two b64
    auto ldlds8 = [](const u16* p) -> f16x8 {
        struct P2 { f16x4 lo, hi; } t;
        t.lo = *(const f16x4*)p;
        t.hi = *(const f16x4*)(p + 4);
        return __builtin_bit_cast(f16x8, t);
    };
    // 8 fp16 from LDS at 4-B alignment: four b32
    auto ldlds4 = [](const u16* p) -> f16x8 {
        struct P4 { unsigned a, b, c, d; } t;
        t.a = *(const unsigned*)(p);
        t.b = *(const unsigned*)(p + 2);
        t.c = *(const unsigned*)(p + 4);
        t.d = *(const unsigned*)(p + 6);
        return __builtin_bit_cast(f16x8, t);
    };

    // ---- prefetch both paths' A-frags for rowtile w (xfr stays live for deferred v) ----
    f16x8 xfr[4], ffr[4];
    #pragma unroll
    for (int ks = 0; ks < 4; ++ks) {
        xfr[ks] = ldf16(xb + (16*w + c) * DIM_ + 32*ks + 8*g);
        ffr[ks] = ldf16(fb + (16*w + c) * DIM_ + 32*ks + 8*g);
    }

    // stage-A GEMM for rowtile w, all 128 cols.
    // which: 0 -> q area (stride 36); 1 -> k area (stride 34);
    //        2 -> vT over k area (stride 68; lane's 4 tokens are contiguous -> b64)
    auto gemmA = [&](const f16x8* afr, int wbase, const float* biasv, int which) {
        #pragma unroll
        for (int lct = 0; lct < 8; ++lct) {
            f32x4 acc = zf4;
            #pragma unroll
            for (int ks = 0; ks < 4; ++ks) {
                f16x8 bfr = *(const f16x8*)(ws + (wbase + 4*lct + ks) * 512 + lane * 8);
                acc = MFMA_F16(afr[ks], bfr, acc);
            }
            float bv = biasv[16*lct + c];
            const int hh = lct >> 1;
            const int cc = ((lct & 1) << 4) + c;
            if (which == 2) {
                // vT[cc][token 16w+4g+0..3]: contiguous, one b64 packed store
                struct H4 { f16x2 lo, hi; } t;
                t.lo = PKRTZ(acc[0] + bv, acc[1] + bv);
                t.hi = PKRTZ(acc[2] + bv, acc[3] + bv);
                *(f16x4*)(smem + hh*HREG + KOFF + cc*SVT + 16*w + 4*g) =
                    __builtin_bit_cast(f16x4, t);
            } else if (which == 1) {
                #pragma unroll
                for (int i = 0; i < 4; ++i)
                    smem[hh*HREG + KOFF + (16*w + 4*g + i)*SK + cc] = f2h_u(acc[i] + bv);
            } else {
                #pragma unroll
                for (int i = 0; i < 4; ++i)
                    smem[hh*HREG + (16*w + 4*g + i)*SQ + cc] = f2h_u(acc[i] + bv);
            }
        }
    };

    // ---- stage x-path: q, k (v deferred) ----
    gemmA(xfr,   0, bq,  0);
    gemmA(xfr,  32, bkv, 1);
    __syncthreads();                                             // (1)

    // ---- S = q k^T (head = w) ----
    f32x4 S[4][4];
    {
        f16x8 qfr[4], kfr[4];
        #pragma unroll
        for (int t = 0; t < 4; ++t) {
            qfr[t] = ldlds8(hb + (16*t + c) * SQ + 8*g);
            kfr[t] = ldlds4(hb + KOFF + (16*t + c) * SK + 8*g);
        }
        #pragma unroll
        for (int mt = 0; mt < 4; ++mt)
            #pragma unroll
            for (int nt = 0; nt < 4; ++nt)
                S[mt][nt] = MFMA_F16(qfr[mt], kfr[nt], zf4);
    }
    __syncthreads();                                             // (2) q/k reads done

    // ---- stage f-path: qf, kf ----
    gemmA(ffr,  96, bq_f,  0);
    gemmA(ffr, 128, bkv_f, 1);
    __syncthreads();                                             // (3)

    // ---- Sf fused with joint modulation: S = (S*scale+b) * (sf*scale+b) ----
    {
        f16x8 kfr[4];
        #pragma unroll
        for (int t = 0; t < 4; ++t)
            kfr[t] = ldlds4(hb + KOFF + (16*t + c) * SK + 8*g);
        #pragma unroll
        for (int mt = 0; mt < 4; ++mt) {
            f16x8 qfr = ldlds8(hb + (16*mt + c) * SQ + 8*g);
            #pragma unroll
            for (int nt = 0; nt < 4; ++nt) {
                f32x4 sf = MFMA_F16(qfr, kfr[nt], zf4);
                int j = 16*nt + c;
                #pragma unroll
                for (int i = 0; i < 4; ++i) {
                    int r = 16*mt + 4*g + i;
                    int idx = ((r >> 3) - (j >> 3) + 7) * 15 + ((r & 7) - (j & 7) + 7);
                    float bv = btab[idx * 4 + w];
                    S[mt][nt][i] = (S[mt][nt][i] * SCALE_ + bv) * (sf[i] * SCALE_ + bv);
                }
            }
        }
    }

    // ---- softmax over rows ----
    float rinv[4][4];
    #pragma unroll
    for (int mt = 0; mt < 4; ++mt)
        #pragma unroll
        for (int i = 0; i < 4; ++i) {
            float m = fmaxf(fmaxf(S[mt][0][i], S[mt][1][i]), fmaxf(S[mt][2][i], S[mt][3][i]));
            #pragma unroll
            for (int d = 1; d < 16; d <<= 1) m = fmaxf(m, __shfl_xor(m, d));
            float s0 = 0.f;
            #pragma unroll
            for (int nt = 0; nt < 4; ++nt) {
                float e = __expf(S[mt][nt][i] - m);
                S[mt][nt][i] = e;
                s0 += e;
            }
            #pragma unroll
            for (int d = 1; d < 16; d <<= 1) s0 += __shfl_xor(s0, d);
            rinv[mt][i] = 1.0f / s0;
        }

    // ---- P-half0 (tokens 0..31 = nt 0,1) -> own q-area, cols 0..31 ----
    // qf dead (own-wave Sf reads already issued; other waves never read head w).
    #pragma unroll
    for (int mt = 0; mt < 4; ++mt)
        #pragma unroll
        for (int i = 0; i < 4; ++i) {
            hb[(16*mt + 4*g + i) * SQ +      c] = f2h_u(S[mt][0][i] * rinv[mt][i]);
            hb[(16*mt + 4*g + i) * SQ + 16 + c] = f2h_u(S[mt][1][i] * rinv[mt][i]);
        }
    __syncthreads();                                             // (4) all kf reads done

    // ---- deferred v-GEMM: vT over all heads' k-areas ----
    gemmA(xfr, 64, bkv + 128, 2);
    __syncthreads();                                             // (5) vT visible

    // ---- O = P @ v : two sequential half-passes over the same P buffer ----
    f32x4 O[4][2] = { { zf4, zf4 }, { zf4, zf4 }, { zf4, zf4 }, { zf4, zf4 } };
    {   // pass 0: tokens 0..31
        f16x8 pfr[4], vfr[2];
        #pragma unroll
        for (int mt = 0; mt < 4; ++mt)
            pfr[mt] = ldlds8(hb + (16*mt + c) * SQ + 8*g);
        #pragma unroll
        for (int nt = 0; nt < 2; ++nt)
            vfr[nt] = ldlds8(hb + KOFF + (16*nt + c) * SVT + 8*g);
        #pragma unroll
        for (int mt = 0; mt < 4; ++mt)
            #pragma unroll
            for (int nt = 0; nt < 2; ++nt)
                O[mt][nt] = MFMA_F16(pfr[mt], vfr[nt], O[mt][nt]);
    }
    // P-half1 (tokens 32..63 = nt 2,3) — after pass-0 reads, same-wave DS order
    #pragma unroll
    for (int mt = 0; mt < 4; ++mt)
        #pragma unroll
        for (int i = 0; i < 4; ++i) {
            hb[(16*mt + 4*g + i) * SQ +      c] = f2h_u(S[mt][2][i] * rinv[mt][i]);
            hb[(16*mt + 4*g + i) * SQ + 16 + c] = f2h_u(S[mt][3][i] * rinv[mt][i]);
        }
    {   // pass 1: tokens 32..63
        f16x8 pfr[4], vfr[2];
        #pragma unroll
        for (int mt = 0; mt < 4; ++mt)
            pfr[mt] = ldlds8(hb + (16*mt + c) * SQ + 8*g);
        #pragma unroll
        for (int nt = 0; nt < 2; ++nt)
            vfr[nt] = ldlds8(hb + KOFF + (16*nt + c) * SVT + 32 + 8*g);
        #pragma unroll
        for (int mt = 0; mt < 4; ++mt)
            #pragma unroll
            for (int nt = 0; nt < 2; ++nt)
                O[mt][nt] = MFMA_F16(pfr[mt], vfr[nt], O[mt][nt]);
    }

    // ---- attn-out (fp16) -> own q-area as [64][36] (P dead; fits: 2299 < 2304) ----
    #pragma unroll
    for (int mt = 0; mt < 4; ++mt)
        #pragma unroll
        for (int nt = 0; nt < 2; ++nt)
            #pragma unroll
            for (int i = 0; i < 4; ++i)
                hb[(16*mt + 4*g + i) * SQ + 16*nt + c] = f2h_u(O[mt][nt][i]);

    __syncthreads();                                             // (6) before cross-head proj

    // ---- proj: wave w -> output cols [32w, 32w+32), K=128 over 4 source heads ----
    f32x4 PO[4][2] = { { zf4, zf4 }, { zf4, zf4 }, { zf4, zf4 }, { zf4, zf4 } };
    #pragma unroll
    for (int ks = 0; ks < 4; ++ks) {
        const u16* ao = smem + ks * HREG;
        f16x8 afr[4];
        #pragma unroll
        for (int mt = 0; mt < 4; ++mt)
            afr[mt] = ldlds8(ao + (16*mt + c) * SQ + 8*g);
        #pragma unroll
        for (int lct = 0; lct < 2; ++lct) {
            f16x8 bfr = *(const f16x8*)(ws + (160 + (2*w + lct) * 4 + ks) * 512 + lane * 8);
            #pragma unroll
            for (int mt = 0; mt < 4; ++mt)
                PO[mt][lct] = MFMA_F16(afr[mt], bfr, PO[mt][lct]);
        }
    }

    // ---- direct global store: 16-lane groups write 64-B runs (full sectors) ----
    float* const ob = out + (size_t)b * 8192;
    #pragma unroll
    for (int lct = 0; lct < 2; ++lct) {
        float bv = bproj[32*w + 16*lct + c];
        #pragma unroll
        for (int mt = 0; mt < 4; ++mt)
            #pragma unroll
            for (int i = 0; i < 4; ++i)
                ob[(16*mt + 4*g + i) * 128 + 32*w + 16*lct + c] = PO[mt][lct][i] + bv;
    }
}

extern "C" void kernel_launch(void* const* d_in, const int* in_sizes, int n_in,
                              void* d_out, int out_size, void* d_ws, size_t ws_size,
                              hipStream_t stream)
{
    const float* x     = (const float*)d_in[0];
    const float* f     = (const float*)d_in[1];
    const float* wq    = (const float*)d_in[2];
    const float* bq    = (const float*)d_in[3];
    const float* wkv   = (const float*)d_in[4];
    const float* bkv   = (const float*)d_in[5];
    const float* wq_f  = (const float*)d_in[6];
    const float* bq_f  = (const float*)d_in[7];
    const float* wkv_f = (const float*)d_in[8];
    const float* bkv_f = (const float*)d_in[9];
    const float* btab  = (const float*)d_in[10];
    const float* wproj = (const float*)d_in[11];
    const float* bproj = (const float*)d_in[12];
    u16* ws    = (u16*)d_ws;
    float* out = (float*)d_out;

    hipLaunchKernelGGL(wja_prep, dim3(192), dim3(64), 0, stream,
                       wq, wkv, wq_f, wkv_f, wproj, ws);
    hipLaunchKernelGGL(wja_fused, dim3(4096), dim3(256), 0, stream,
                       x, f, bq, bkv, bq_f, bkv_f, bproj, btab, ws, out);
}

// Round 16
// 198.969 us; speedup vs baseline: 1.4421x; 1.4421x over previous
//
#include <hip/hip_runtime.h>

typedef unsigned short u16;
typedef _Float16  f16x8  __attribute__((ext_vector_type(8)));
typedef _Float16  f16x4  __attribute__((ext_vector_type(4)));
typedef _Float16  f16x2  __attribute__((ext_vector_type(2)));
typedef float     f32x4  __attribute__((ext_vector_type(4)));

#define MFMA_F16(a,b,c)  __builtin_amdgcn_mfma_f32_16x16x32_f16(a,b,c,0,0,0)
#define PKRTZ(a,b) __builtin_bit_cast(f16x2, __builtin_amdgcn_cvt_pkrtz((a),(b)))

#define NTOK 64
#define DIM_ 128
#define SCALE_ 0.17677669529663687f   // 32^-0.5

// LDS geometry (u16 units) — R8/R13 layout (54272 B, low-conflict strides)
#define HREG 6784      // per-head: q[64][36] | k[64][36] | vT[32][68]
#define KOFF 2304      // 64*36
#define VOFF 4608      // 2*64*36
#define SQK  36        // q/k stride (72-B rows, 8-B aligned)
#define SP   72        // P stride (144-B rows, 16-B aligned); 64*72=4608 exact over q+k
#define SAO  40        // attn-out stride (80-B rows, 16-B aligned)
#define SVT  68        // vT stride (136-B rows, 8-B aligned)
#define SMEM_U16 27136 // 4*HREG = 54272 B

__device__ __forceinline__ u16 f2h_u(float x) {
    _Float16 h = (_Float16)x;
    return __builtin_bit_cast(u16, h);
}

// ---------------- prep: repack f32 weights into fp16 MFMA B-fragment order ----------------
// ws: u16 frags [192*512]: [wq 0..31 | wkv 32..95 | wq_f 96..127 | wkv_f(k-half) 128..159 | wproj 160..191]
__global__ void wja_prep(const float* __restrict__ wq, const float* __restrict__ wkv,
                         const float* __restrict__ wq_f, const float* __restrict__ wkv_f,
                         const float* __restrict__ wproj, u16* __restrict__ ws)
{
    const int blk = blockIdx.x;
    const int l = threadIdx.x;          // 64 threads
    const float* W; int ldw, colbase;
    if (blk < 32)       { W = wq;    ldw = 128; colbase = (blk      >> 2) * 16; }
    else if (blk < 96)  { W = wkv;   ldw = 256; colbase = ((blk- 32) >> 2) * 16; }
    else if (blk < 128) { W = wq_f;  ldw = 128; colbase = ((blk- 96) >> 2) * 16; }
    else if (blk < 160) { W = wkv_f; ldw = 256; colbase = ((blk-128) >> 2) * 16; }
    else                { W = wproj; ldw = 128; colbase = ((blk-160) >> 2) * 16; }
    const int ks = blk & 3;
    const int m = l & 15, g = l >> 4;
    u16* dst = ws + blk * 512 + l * 8;
    #pragma unroll
    for (int i = 0; i < 8; ++i)
        dst[i] = f2h_u(W[(size_t)(32*ks + 8*g + i) * ldw + colbase + m]);
}

// ---------------- fused window joint attention ----------------
// 1 block = 1 window; 4 waves. Stage-A: wave w = 16-token rowtile (all heads).
// Attention phases: wave w = head w. 4 barriers. R13 champion structure
// (195 us, VGPR 92, no spills, 2 blocks/CU) + two pressure-neutral tweaks:
//  - SCALE folded into q/qf staging (modulation loses 2 muls/elem)
//  - s_setprio(1) around S/Sf/PV MFMA clusters (2 independent blocks/CU)
// Occupancy is pinned ~8 waves/CU regardless of LDS (R5/R8/R9/R15 evidence)
// — do not chase it. Bias stays INLINE MATH (R12 spill lesson).
__global__ __launch_bounds__(256, 2)
void wja_fused(
    const float* __restrict__ x, const float* __restrict__ f,
    const float* __restrict__ bq, const float* __restrict__ bkv,
    const float* __restrict__ bq_f, const float* __restrict__ bkv_f,
    const float* __restrict__ bproj, const float* __restrict__ btab,
    const u16* __restrict__ ws, float* __restrict__ out)
{
    __shared__ __align__(16) u16 smem[SMEM_U16];
    const int b    = blockIdx.x;
    const int tid  = threadIdx.x;
    const int w    = tid >> 6;        // stage-A: rowtile; attention: head
    const int lane = tid & 63;
    const int g    = lane >> 4;
    const int c    = lane & 15;
    const f32x4 zf4 = {0.f, 0.f, 0.f, 0.f};

    u16* const hb = smem + w * HREG;  // own head region in attention phases

    const float* const xb = x + (size_t)b * (NTOK * DIM_);
    const float* const fb = f + (size_t)b * (NTOK * DIM_);

    // 8 f32 -> f16x8 via two vector loads + 4 packed cvt (RTZ)
    auto ldf16 = [](const float* p) -> f16x8 {
        f32x4 v0 = *(const f32x4*)p;
        f32x4 v1 = *(const f32x4*)(p + 4);
        struct Q { f16x2 a, b, c, d; } t;
        t.a = PKRTZ(v0[0], v0[1]);
        t.b = PKRTZ(v0[2], v0[3]);
        t.c = PKRTZ(v1[0], v1[1]);
        t.d = PKRTZ(v1[2], v1[3]);
        return __builtin_bit_cast(f16x8, t);
    };
    // 8 fp16 from LDS at 8-B alignment: two b64
    auto ldlds8 = [](const u16* p) -> f16x8 {
        struct P2 { f16x4 lo, hi; } t;
        t.lo = *(const f16x4*)p;
        t.hi = *(const f16x4*)(p + 4);
        return __builtin_bit_cast(f16x8, t);
    };

    // ---- prefetch both paths' A-frags for rowtile w ----
    f16x8 xfr[4], ffr[4];
    #pragma unroll
    for (int ks = 0; ks < 4; ++ks) {
        xfr[ks] = ldf16(xb + (16*w + c) * DIM_ + 32*ks + 8*g);
        ffr[ks] = ldf16(fb + (16*w + c) * DIM_ + 32*ks + 8*g);
    }

    // stage-A GEMM for rowtile w, all 128 cols.
    // which: 0 -> q area, scaled by SCALE_ (folds softmax scale);
    //        1 -> k area; 2 -> vT (transposed, packed b64 writes)
    auto gemmA = [&](const f16x8* afr, int wbase, const float* biasv, int which) {
        #pragma unroll
        for (int lct = 0; lct < 8; ++lct) {
            f32x4 acc = zf4;
            #pragma unroll
            for (int ks = 0; ks < 4; ++ks) {
                f16x8 bfr = *(const f16x8*)(ws + (wbase + 4*lct + ks) * 512 + lane * 8);
                acc = MFMA_F16(afr[ks], bfr, acc);
            }
            float bv = biasv[16*lct + c];
            const int hh = lct >> 1;
            const int cc = ((lct & 1) << 4) + c;
            if (which == 2) {
                // rows 16w+4g..+3 consecutive at col cc: one b64 packed store
                struct H4 { f16x2 lo, hi; } t;
                t.lo = PKRTZ(acc[0] + bv, acc[1] + bv);
                t.hi = PKRTZ(acc[2] + bv, acc[3] + bv);
                *(f16x4*)(smem + hh*HREG + VOFF + cc*SVT + 16*w + 4*g) =
                    __builtin_bit_cast(f16x4, t);
            } else if (which == 1) {
                #pragma unroll
                for (int i = 0; i < 4; ++i)
                    smem[hh*HREG + KOFF + (16*w + 4*g + i)*SQK + cc] = f2h_u(acc[i] + bv);
            } else {
                #pragma unroll
                for (int i = 0; i < 4; ++i)
                    smem[hh*HREG + (16*w + 4*g + i)*SQK + cc] = f2h_u((acc[i] + bv) * SCALE_);
            }
        }
    };

    // ---- stage x-path: q (scaled), k, vT ----
    gemmA(xfr,   0, bq,        0);
    gemmA(xfr,  32, bkv,       1);
    gemmA(xfr,  64, bkv + 128, 2);
    __syncthreads();                                             // (1)

    // ---- S' = (q*scale) k^T (head = w) ----
    f32x4 S[4][4];
    {
        f16x8 qfr[4], kfr[4];
        #pragma unroll
        for (int t = 0; t < 4; ++t) {
            qfr[t] = ldlds8(hb + (16*t + c) * SQK + 8*g);
            kfr[t] = ldlds8(hb + KOFF + (16*t + c) * SQK + 8*g);
        }
        __builtin_amdgcn_s_setprio(1);
        #pragma unroll
        for (int mt = 0; mt < 4; ++mt)
            #pragma unroll
            for (int nt = 0; nt < 4; ++nt)
                S[mt][nt] = MFMA_F16(qfr[mt], kfr[nt], zf4);
        __builtin_amdgcn_s_setprio(0);
    }
    __syncthreads();                                             // (2) q/k reads done

    // ---- stage f-path: qf (scaled), kf ----
    gemmA(ffr,  96, bq_f,  0);
    gemmA(ffr, 128, bkv_f, 1);
    __syncthreads();                                             // (3)

    // ---- Sf fused with joint modulation: S = (S'+b) * (sf'+b) (scales pre-folded) ----
    {
        f16x8 kfr[4];
        #pragma unroll
        for (int t = 0; t < 4; ++t)
            kfr[t] = ldlds8(hb + KOFF + (16*t + c) * SQK + 8*g);
        #pragma unroll
        for (int mt = 0; mt < 4; ++mt) {
            f16x8 qfr = ldlds8(hb + (16*mt + c) * SQK + 8*g);
            __builtin_amdgcn_s_setprio(1);
            #pragma unroll
            for (int nt = 0; nt < 4; ++nt) {
                f32x4 sf = MFMA_F16(qfr, kfr[nt], zf4);
                int j = 16*nt + c;
                #pragma unroll
                for (int i = 0; i < 4; ++i) {
                    int r = 16*mt + 4*g + i;
                    int idx = ((r >> 3) - (j >> 3) + 7) * 15 + ((r & 7) - (j & 7) + 7);
                    float bv = btab[idx * 4 + w];
                    S[mt][nt][i] = (S[mt][nt][i] + bv) * (sf[i] + bv);
                }
            }
            __builtin_amdgcn_s_setprio(0);
        }
    }

    // ---- softmax over rows ----
    float rinv[4][4];
    #pragma unroll
    for (int mt = 0; mt < 4; ++mt)
        #pragma unroll
        for (int i = 0; i < 4; ++i) {
            float m = fmaxf(fmaxf(S[mt][0][i], S[mt][1][i]), fmaxf(S[mt][2][i], S[mt][3][i]));
            #pragma unroll
            for (int d = 1; d < 16; d <<= 1) m = fmaxf(m, __shfl_xor(m, d));
            float s0 = 0.f;
            #pragma unroll
            for (int nt = 0; nt < 4; ++nt) {
                float e = __expf(S[mt][nt][i] - m);
                S[mt][nt][i] = e;
                s0 += e;
            }
            #pragma unroll
            for (int d = 1; d < 16; d <<= 1) s0 += __shfl_xor(s0, d);
            rinv[mt][i] = 1.0f / s0;
        }

    // ---- P (fp16) -> own head region, stride 72 (same-wave in-order, no barrier) ----
    #pragma unroll
    for (int mt = 0; mt < 4; ++mt)
        #pragma unroll
        for (int nt = 0; nt < 4; ++nt)
            #pragma unroll
            for (int i = 0; i < 4; ++i)
                hb[(16*mt + 4*g + i) * SP + 16*nt + c] = f2h_u(S[mt][nt][i] * rinv[mt][i]);

    // ---- O = P @ v (K=64 via vT) ----
    f32x4 O[4][2] = { { zf4, zf4 }, { zf4, zf4 }, { zf4, zf4 }, { zf4, zf4 } };
    #pragma unroll
    for (int ks = 0; ks < 2; ++ks) {
        f16x8 pfr[4], vfr[2];
        #pragma unroll
        for (int mt = 0; mt < 4; ++mt)
            pfr[mt] = *(const f16x8*)(hb + (16*mt + c) * SP + 32*ks + 8*g);  // 16-B aligned
        #pragma unroll
        for (int nt = 0; nt < 2; ++nt)
            vfr[nt] = ldlds8(hb + VOFF + (16*nt + c) * SVT + 32*ks + 8*g);
        __builtin_amdgcn_s_setprio(1);
        #pragma unroll
        for (int mt = 0; mt < 4; ++mt)
            #pragma unroll
            for (int nt = 0; nt < 2; ++nt)
                O[mt][nt] = MFMA_F16(pfr[mt], vfr[nt], O[mt][nt]);
        __builtin_amdgcn_s_setprio(0);
    }

    // ---- attn-out (fp16) -> own head region as [64][40] ----
    #pragma unroll
    for (int mt = 0; mt < 4; ++mt)
        #pragma unroll
        for (int nt = 0; nt < 2; ++nt)
            #pragma unroll
            for (int i = 0; i < 4; ++i)
                hb[(16*mt + 4*g + i) * SAO + 16*nt + c] = f2h_u(O[mt][nt][i]);

    __syncthreads();                                             // (4) before cross-head proj

    // ---- proj: wave w -> output cols [32w, 32w+32), K=128 over 4 source heads ----
    f32x4 PO[4][2] = { { zf4, zf4 }, { zf4, zf4 }, { zf4, zf4 }, { zf4, zf4 } };
    #pragma unroll
    for (int ks = 0; ks < 4; ++ks) {
        const u16* ao = smem + ks * HREG;
        f16x8 afr[4];
        #pragma unroll
        for (int mt = 0; mt < 4; ++mt)
            afr[mt] = *(const f16x8*)(ao + (16*mt + c) * SAO + 8*g);         // 16-B aligned
        #pragma unroll
        for (int lct = 0; lct < 2; ++lct) {
            f16x8 bfr = *(const f16x8*)(ws + (160 + (2*w + lct) * 4 + ks) * 512 + lane * 8);
            #pragma unroll
            for (int mt = 0; mt < 4; ++mt)
                PO[mt][lct] = MFMA_F16(afr[mt], bfr, PO[mt][lct]);
        }
    }

    // ---- direct global store: 16-lane groups write 64-B runs (full sectors) ----
    float* const ob = out + (size_t)b * 8192;
    #pragma unroll
    for (int lct = 0; lct < 2; ++lct) {
        float bv = bproj[32*w + 16*lct + c];
        #pragma unroll
        for (int mt = 0; mt < 4; ++mt)
            #pragma unroll
            for (int i = 0; i < 4; ++i)
                ob[(16*mt + 4*g + i) * 128 + 32*w + 16*lct + c] = PO[mt][lct][i] + bv;
    }
}

extern "C" void kernel_launch(void* const* d_in, const int* in_sizes, int n_in,
                              void* d_out, int out_size, void* d_ws, size_t ws_size,
                              hipStream_t stream)
{
    const float* x     = (const float*)d_in[0];
    const float* f     = (const float*)d_in[1];
    const float* wq    = (const float*)d_in[2];
    const float* bq    = (const float*)d_in[3];
    const float* wkv   = (const float*)d_in[4];
    const float* bkv   = (const float*)d_in[5];
    const float* wq_f  = (const float*)d_in[6];
    const float* bq_f  = (const float*)d_in[7];
    const float* wkv_f = (const float*)d_in[8];
    const float* bkv_f = (const float*)d_in[9];
    const float* btab  = (const float*)d_in[10];
    const float* wproj = (const float*)d_in[11];
    const float* bproj = (const float*)d_in[12];
    u16* ws    = (u16*)d_ws;
    float* out = (float*)d_out;

    hipLaunchKernelGGL(wja_prep, dim3(192), dim3(64), 0, stream,
                       wq, wkv, wq_f, wkv_f, wproj, ws);
    hipLaunchKernelGGL(wja_fused, dim3(4096), dim3(256), 0, stream,
                       x, f, bq, bkv, bq_f, bkv_f, bproj, btab, ws, out);
}

// Round 17
// 185.091 us; speedup vs baseline: 1.5503x; 1.0750x over previous
//
#include <hip/hip_runtime.h>

typedef unsigned short u16;
typedef _Float16  f16x8  __attribute__((ext_vector_type(8)));
typedef _Float16  f16x4  __attribute__((ext_vector_type(4)));
typedef _Float16  f16x2  __attribute__((ext_vector_type(2)));
typedef float     f32x4  __attribute__((ext_vector_type(4)));

#define MFMA_F16(a,b,c)  __builtin_amdgcn_mfma_f32_16x16x32_f16(a,b,c,0,0,0)
#define PKRTZ(a,b) __builtin_bit_cast(f16x2, __builtin_amdgcn_cvt_pkrtz((a),(b)))

#define NTOK 64
#define DIM_ 128
#define SCALE_ 0.17677669529663687f   // 32^-0.5

// LDS geometry (u16 units) — R8/R13 layout (54272 B, low-conflict strides)
#define HREG 6784      // per-head: q[64][36] | k[64][36] | vT[32][68]
#define KOFF 2304      // 64*36
#define VOFF 4608      // 2*64*36
#define SQK  36        // q/k stride (72-B rows, 8-B aligned)
#define SP   72        // P stride (144-B rows, 16-B aligned); 64*72=4608 exact over q+k
#define SAO  40        // attn-out stride (80-B rows, 16-B aligned)
#define SVT  68        // vT stride (136-B rows, 8-B aligned)
#define SMEM_U16 27136 // 4*HREG = 54272 B

// ws layout: u16 frags [192*512] = 196608 B, then f32 bias tile-table
// [4][4][4][4][16][4] (h,mt,nt,g,c,i) at f32-offset 49152 (bytes 196608..262144).
// ws_size >= 262144 is PROVEN: R5 passed reading this exact range.
#define WS_TAB_F32 49152

__device__ __forceinline__ u16 f2h_u(float x) {
    _Float16 h = (_Float16)x;
    return __builtin_bit_cast(u16, h);
}

// ---------------- prep: repack weights to fp16 B-frag order + bias tile-table ----------------
__global__ void wja_prep(const float* __restrict__ wq, const float* __restrict__ wkv,
                         const float* __restrict__ wq_f, const float* __restrict__ wkv_f,
                         const float* __restrict__ wproj, const float* __restrict__ btab,
                         u16* __restrict__ ws)
{
    const int blk = blockIdx.x;
    const int l = threadIdx.x;          // 64 threads
    if (blk < 192) {
        const float* W; int ldw, colbase;
        if (blk < 32)       { W = wq;    ldw = 128; colbase = (blk      >> 2) * 16; }
        else if (blk < 96)  { W = wkv;   ldw = 256; colbase = ((blk- 32) >> 2) * 16; }
        else if (blk < 128) { W = wq_f;  ldw = 128; colbase = ((blk- 96) >> 2) * 16; }
        else if (blk < 160) { W = wkv_f; ldw = 256; colbase = ((blk-128) >> 2) * 16; }
        else                { W = wproj; ldw = 128; colbase = ((blk-160) >> 2) * 16; }
        const int ks = blk & 3;
        const int m = l & 15, g = l >> 4;
        u16* dst = ws + blk * 512 + l * 8;
        #pragma unroll
        for (int i = 0; i < 8; ++i)
            dst[i] = f2h_u(W[(size_t)(32*ks + 8*g + i) * ldw + colbase + m]);
    } else {
        // bias tile-table for head h: tab[e], e = (((mt*4+nt)*4+g)*16+c)*4+i
        const int h = blk - 192;
        float* tab = (float*)ws + WS_TAB_F32 + h * 4096;
        for (int e = l; e < 4096; e += 64) {
            int i  = e & 3;
            int cc = (e >> 2) & 15;
            int g  = (e >> 6) & 3;
            int nt = (e >> 8) & 3;
            int mt = (e >> 10) & 3;
            int r = 16*mt + 4*g + i;
            int j = 16*nt + cc;
            int idx = ((r >> 3) - (j >> 3) + 7) * 15 + ((r & 7) - (j & 7) + 7);
            tab[e] = btab[idx * 4 + h];
        }
    }
}

// ---------------- fused window joint attention ----------------
// 1 block = 1 window; 4 waves. Stage-A: wave w = 16-token rowtile (all heads).
// Attention: wave w = head w. 4 barriers. R13 champion structure +
//  - SCALE folded into q/qf staging
//  - bias via MFMA C-operand init (loads land IN the accumulator regs ->
//    zero extra VGPR pressure; kills ~700 VALU-slots of idx math/phase)
//  - softmax normalization deferred to attn-out (32 muls not 64), rcp for 1/sum
// Occupancy pinned ~8 waves/CU regardless of LDS (R5-R15) — not chased.
__global__ __launch_bounds__(256, 2)
void wja_fused(
    const float* __restrict__ x, const float* __restrict__ f,
    const float* __restrict__ bq, const float* __restrict__ bkv,
    const float* __restrict__ bq_f, const float* __restrict__ bkv_f,
    const float* __restrict__ bproj,
    const u16* __restrict__ ws, float* __restrict__ out)
{
    __shared__ __align__(16) u16 smem[SMEM_U16];
    const int b    = blockIdx.x;
    const int tid  = threadIdx.x;
    const int w    = tid >> 6;        // stage-A: rowtile; attention: head
    const int lane = tid & 63;
    const int g    = lane >> 4;
    const int c    = lane & 15;
    const f32x4 zf4 = {0.f, 0.f, 0.f, 0.f};

    u16* const hb = smem + w * HREG;  // own head region in attention phases
    const float* const tabw = (const float*)ws + WS_TAB_F32 + w * 4096;

    const float* const xb = x + (size_t)b * (NTOK * DIM_);
    const float* const fb = f + (size_t)b * (NTOK * DIM_);

    // 8 f32 -> f16x8 via two vector loads + 4 packed cvt (RTZ)
    auto ldf16 = [](const float* p) -> f16x8 {
        f32x4 v0 = *(const f32x4*)p;
        f32x4 v1 = *(const f32x4*)(p + 4);
        struct Q { f16x2 a, b, c, d; } t;
        t.a = PKRTZ(v0[0], v0[1]);
        t.b = PKRTZ(v0[2], v0[3]);
        t.c = PKRTZ(v1[0], v1[1]);
        t.d = PKRTZ(v1[2], v1[3]);
        return __builtin_bit_cast(f16x8, t);
    };
    // 8 fp16 from LDS at 8-B alignment: two b64
    auto ldlds8 = [](const u16* p) -> f16x8 {
        struct P2 { f16x4 lo, hi; } t;
        t.lo = *(const f16x4*)p;
        t.hi = *(const f16x4*)(p + 4);
        return __builtin_bit_cast(f16x8, t);
    };
    // bias tile for (mt,nt): one f32x4 per thread, lands in the MFMA acc regs
    auto btile = [&](int mt, int nt) -> f32x4 {
        return *(const f32x4*)(tabw + ((mt*4 + nt)*4 + g)*64 + c*4);
    };

    // ---- prefetch both paths' A-frags for rowtile w ----
    f16x8 xfr[4], ffr[4];
    #pragma unroll
    for (int ks = 0; ks < 4; ++ks) {
        xfr[ks] = ldf16(xb + (16*w + c) * DIM_ + 32*ks + 8*g);
        ffr[ks] = ldf16(fb + (16*w + c) * DIM_ + 32*ks + 8*g);
    }

    // stage-A GEMM for rowtile w, all 128 cols.
    // which: 0 -> q area, scaled by SCALE_; 1 -> k area; 2 -> vT (packed b64)
    auto gemmA = [&](const f16x8* afr, int wbase, const float* biasv, int which) {
        #pragma unroll
        for (int lct = 0; lct < 8; ++lct) {
            f32x4 acc = zf4;
            #pragma unroll
            for (int ks = 0; ks < 4; ++ks) {
                f16x8 bfr = *(const f16x8*)(ws + (wbase + 4*lct + ks) * 512 + lane * 8);
                acc = MFMA_F16(afr[ks], bfr, acc);
            }
            float bv = biasv[16*lct + c];
            const int hh = lct >> 1;
            const int cc = ((lct & 1) << 4) + c;
            if (which == 2) {
                struct H4 { f16x2 lo, hi; } t;
                t.lo = PKRTZ(acc[0] + bv, acc[1] + bv);
                t.hi = PKRTZ(acc[2] + bv, acc[3] + bv);
                *(f16x4*)(smem + hh*HREG + VOFF + cc*SVT + 16*w + 4*g) =
                    __builtin_bit_cast(f16x4, t);
            } else if (which == 1) {
                #pragma unroll
                for (int i = 0; i < 4; ++i)
                    smem[hh*HREG + KOFF + (16*w + 4*g + i)*SQK + cc] = f2h_u(acc[i] + bv);
            } else {
                #pragma unroll
                for (int i = 0; i < 4; ++i)
                    smem[hh*HREG + (16*w + 4*g + i)*SQK + cc] = f2h_u((acc[i] + bv) * SCALE_);
            }
        }
    };

    // ---- stage x-path: q (scaled), k, vT ----
    gemmA(xfr,   0, bq,        0);
    gemmA(xfr,  32, bkv,       1);
    gemmA(xfr,  64, bkv + 128, 2);
    __syncthreads();                                             // (1)

    // ---- S = (q*scale) k^T + bias  (bias enters as MFMA C-init) ----
    f32x4 S[4][4];
    {
        f16x8 qfr[4], kfr[4];
        #pragma unroll
        for (int t = 0; t < 4; ++t) {
            qfr[t] = ldlds8(hb + (16*t + c) * SQK + 8*g);
            kfr[t] = ldlds8(hb + KOFF + (16*t + c) * SQK + 8*g);
        }
        #pragma unroll
        for (int mt = 0; mt < 4; ++mt)
            #pragma unroll
            for (int nt = 0; nt < 4; ++nt)
                S[mt][nt] = MFMA_F16(qfr[mt], kfr[nt], btile(mt, nt));
    }
    __syncthreads();                                             // (2) q/k reads done

    // ---- stage f-path: qf (scaled), kf ----
    gemmA(ffr,  96, bq_f,  0);
    gemmA(ffr, 128, bkv_f, 1);
    __syncthreads();                                             // (3)

    // ---- Sf (+bias via C-init) fused with joint modulation: S *= Sf ----
    {
        f16x8 kfr[4];
        #pragma unroll
        for (int t = 0; t < 4; ++t)
            kfr[t] = ldlds8(hb + KOFF + (16*t + c) * SQK + 8*g);
        #pragma unroll
        for (int mt = 0; mt < 4; ++mt) {
            f16x8 qfr = ldlds8(hb + (16*mt + c) * SQK + 8*g);
            #pragma unroll
            for (int nt = 0; nt < 4; ++nt) {
                f32x4 sf = MFMA_F16(qfr, kfr[nt], btile(mt, nt));
                #pragma unroll
                for (int i = 0; i < 4; ++i)
                    S[mt][nt][i] *= sf[i];
            }
        }
    }

    // ---- softmax over rows (normalization deferred to attn-out) ----
    float rinv[4][4];
    #pragma unroll
    for (int mt = 0; mt < 4; ++mt)
        #pragma unroll
        for (int i = 0; i < 4; ++i) {
            float m = fmaxf(fmaxf(S[mt][0][i], S[mt][1][i]), fmaxf(S[mt][2][i], S[mt][3][i]));
            #pragma unroll
            for (int d = 1; d < 16; d <<= 1) m = fmaxf(m, __shfl_xor(m, d));
            float s0 = 0.f;
            #pragma unroll
            for (int nt = 0; nt < 4; ++nt) {
                float e = __expf(S[mt][nt][i] - m);
                S[mt][nt][i] = e;
                s0 += e;
            }
            #pragma unroll
            for (int d = 1; d < 16; d <<= 1) s0 += __shfl_xor(s0, d);
            rinv[mt][i] = __builtin_amdgcn_rcpf(s0);
        }

    // ---- P (unnormalized exp, fp16) -> own head region, stride 72 ----
    #pragma unroll
    for (int mt = 0; mt < 4; ++mt)
        #pragma unroll
        for (int nt = 0; nt < 4; ++nt)
            #pragma unroll
            for (int i = 0; i < 4; ++i)
                hb[(16*mt + 4*g + i) * SP + 16*nt + c] = f2h_u(S[mt][nt][i]);

    // ---- O = P @ v (K=64 via vT) ----
    f32x4 O[4][2] = { { zf4, zf4 }, { zf4, zf4 }, { zf4, zf4 }, { zf4, zf4 } };
    #pragma unroll
    for (int ks = 0; ks < 2; ++ks) {
        f16x8 pfr[4], vfr[2];
        #pragma unroll
        for (int mt = 0; mt < 4; ++mt)
            pfr[mt] = *(const f16x8*)(hb + (16*mt + c) * SP + 32*ks + 8*g);  // 16-B aligned
        #pragma unroll
        for (int nt = 0; nt < 2; ++nt)
            vfr[nt] = ldlds8(hb + VOFF + (16*nt + c) * SVT + 32*ks + 8*g);
        #pragma unroll
        for (int mt = 0; mt < 4; ++mt)
            #pragma unroll
            for (int nt = 0; nt < 2; ++nt)
                O[mt][nt] = MFMA_F16(pfr[mt], vfr[nt], O[mt][nt]);
    }

    // ---- attn-out (normalized here, fp16) -> own head region as [64][40] ----
    #pragma unroll
    for (int mt = 0; mt < 4; ++mt)
        #pragma unroll
        for (int nt = 0; nt < 2; ++nt)
            #pragma unroll
            for (int i = 0; i < 4; ++i)
                hb[(16*mt + 4*g + i) * SAO + 16*nt + c] = f2h_u(O[mt][nt][i] * rinv[mt][i]);

    __syncthreads();                                             // (4) before cross-head proj

    // ---- proj: wave w -> output cols [32w, 32w+32), K=128 over 4 source heads ----
    f32x4 PO[4][2] = { { zf4, zf4 }, { zf4, zf4 }, { zf4, zf4 }, { zf4, zf4 } };
    #pragma unroll
    for (int ks = 0; ks < 4; ++ks) {
        const u16* ao = smem + ks * HREG;
        f16x8 afr[4];
        #pragma unroll
        for (int mt = 0; mt < 4; ++mt)
            afr[mt] = *(const f16x8*)(ao + (16*mt + c) * SAO + 8*g);         // 16-B aligned
        #pragma unroll
        for (int lct = 0; lct < 2; ++lct) {
            f16x8 bfr = *(const f16x8*)(ws + (160 + (2*w + lct) * 4 + ks) * 512 + lane * 8);
            #pragma unroll
            for (int mt = 0; mt < 4; ++mt)
                PO[mt][lct] = MFMA_F16(afr[mt], bfr, PO[mt][lct]);
        }
    }

    // ---- direct global store: 16-lane groups write 64-B runs (full sectors) ----
    float* const ob = out + (size_t)b * 8192;
    #pragma unroll
    for (int lct = 0; lct < 2; ++lct) {
        float bv = bproj[32*w + 16*lct + c];
        #pragma unroll
        for (int mt = 0; mt < 4; ++mt)
            #pragma unroll
            for (int i = 0; i < 4; ++i)
                ob[(16*mt + 4*g + i) * 128 + 32*w + 16*lct + c] = PO[mt][lct][i] + bv;
    }
}

extern "C" void kernel_launch(void* const* d_in, const int* in_sizes, int n_in,
                              void* d_out, int out_size, void* d_ws, size_t ws_size,
                              hipStream_t stream)
{
    const float* x     = (const float*)d_in[0];
    const float* f     = (const float*)d_in[1];
    const float* wq    = (const float*)d_in[2];
    const float* bq    = (const float*)d_in[3];
    const float* wkv   = (const float*)d_in[4];
    const float* bkv   = (const float*)d_in[5];
    const float* wq_f  = (const float*)d_in[6];
    const float* bq_f  = (const float*)d_in[7];
    const float* wkv_f = (const float*)d_in[8];
    const float* bkv_f = (const float*)d_in[9];
    const float* btab  = (const float*)d_in[10];
    const float* wproj = (const float*)d_in[11];
    const float* bproj = (const float*)d_in[12];
    u16* ws    = (u16*)d_ws;
    float* out = (float*)d_out;

    hipLaunchKernelGGL(wja_prep, dim3(196), dim3(64), 0, stream,
                       wq, wkv, wq_f, wkv_f, wproj, btab, ws);
    hipLaunchKernelGGL(wja_fused, dim3(4096), dim3(256), 0, stream,
                       x, f, bq, bkv, bq_f, bkv_f, bproj, ws, out);
}